// Round 2
// baseline (539.842 us; speedup 1.0000x reference)
//
#include <hip/hip_runtime.h>
#include <cstdint>
#include <cstddef>

#define Bn 64
#define Hn 56
#define Wn 56
#define Cn 256
#define RWn 64                              // route width = 256/4
#define XSZ ((size_t)Bn * Hn * Wn * RWn)    // 12,845,056 floats
#define RSTRIDE (Wn * Cn)                   // floats between rows
#define BPB (Wn / 4)                        // 14 blocks per batch

__device__ __forceinline__ void f4add(float4& a, const float4& v) {
    a.x += v.x; a.y += v.y; a.z += v.z; a.w += v.w;
}
__device__ __forceinline__ float4 f4sub(const float4& a, const float4& b) {
    return make_float4(a.x - b.x, a.y - b.y, a.z - b.z, a.w - b.w);
}

// ---------------------------------------------------------------------------
// kAB: phase 1 = per-(batch, column) row-class sums (one WAVE per column,
// pure-accumulate loop with first/last pairs PEELED so r0/r54/r55 come from
// registers, not evicted cache — saves ~11 MB HBM re-fetch, bit-identical
// order). Then LAST-BLOCK-DONE tail: each of the 14 blocks of batch b bumps
// cnt[b] (device-scope atomic, fenced); the block seeing old==13 runs the
// whole logits phase for batch b inline. No spin, no co-residency assumption
// -> cannot deadlock (the cooperative grid.sync version killed the container
// under graph capture).
// ---------------------------------------------------------------------------
__global__ __launch_bounds__(256, 4) void kAB(
        const float* __restrict__ in,
        const float* __restrict__ convw, const float* __restrict__ convb,
        const float* __restrict__ fcw,   const float* __restrict__ fcb,
        float* __restrict__ V, int* __restrict__ cnt,
        float* __restrict__ out_logits, int* __restrict__ routes) {
    const int blk = blockIdx.x;
    const int t   = threadIdx.x;
    const int b   = blk / BPB;
    const int wg  = blk - b * BPB;

    __shared__ float sS[9 * 256];
    __shared__ float pP[4][64];
    __shared__ float pld[64];
    __shared__ float lgt[4];
    __shared__ int   isLast;

    // ---------------- phase 1: column row-class sums -> V ----------------
    {
        const int lane = t & 63;
        const int wave = t >> 6;
        const int w    = wg * 4 + wave;

        const float* col = in + ((size_t)b * Hn * Wn + (size_t)w) * Cn
                              + (size_t)lane * 4;

        // peeled first pair (h = 0,1): keep r0 live in registers
        const float4 r0 = *(const float4*)(col);
        const float4 r1 = *(const float4*)(col + (size_t)RSTRIDE);
        float4 A  = r0;   // even rows 0..54
        float4 Bv = r1;   // odd  rows 1..55
#pragma unroll
        for (int h = 2; h < 54; h += 2) {
            f4add(A,  *(const float4*)(col + (size_t)h * RSTRIDE));
            f4add(Bv, *(const float4*)(col + (size_t)(h + 1) * RSTRIDE));
        }
        // peeled last pair (h = 54,55): keep r54/r55 live in registers
        const float4 r54 = *(const float4*)(col + (size_t)54 * RSTRIDE);
        const float4 r55 = *(const float4*)(col + (size_t)55 * RSTRIDE);
        f4add(A, r54);
        f4add(Bv, r55);

        const float4 T0 = f4sub(A,  r54);   // even h <= 52 (kh = 0)
        const float4 T2 = f4sub(A,  r0);    // even h >= 2  (kh = 2)
        const float4 T1 = f4sub(Bv, r55);   // odd  h <= 53 (kh = 1)

        float4* op = (float4*)(V + (((size_t)b * Wn + w) * 3) * 256) + lane;
        op[0]   = T0;      // cls 0, 1KB coalesced per wave
        op[64]  = T1;      // cls 1
        op[128] = T2;      // cls 2
    }

    // -------- last-block-done handoff (device-scope, residency-free) -----
    __threadfence();                 // release: V writes visible device-wide
    __syncthreads();                 // all threads' stores issued + fenced
    if (t == 0)
        isLast = (atomicAdd(&cnt[b], 1) == BPB - 1);
    __syncthreads();
    if (!isLast) return;
    __threadfence();                 // acquire: see other blocks' V writes

    // ---------------- phase 2: logits + route for batch b ----------------
    {
        const float* Vb = V + (size_t)b * Wn * 3 * 256;
        float Ae[3] = {0.f, 0.f, 0.f};   // even-w sums per row-class
        float Bo[3] = {0.f, 0.f, 0.f};   // odd-w sums per row-class
#pragma unroll
        for (int w = 0; w < Wn; w += 2) {
#pragma unroll
            for (int kh = 0; kh < 3; ++kh) {
                Ae[kh] += Vb[((w    ) * 3 + kh) * 256 + t];
                Bo[kh] += Vb[((w + 1) * 3 + kh) * 256 + t];
            }
        }
#pragma unroll
        for (int kh = 0; kh < 3; ++kh) {
            const float t0  = Vb[(0  * 3 + kh) * 256 + t];
            const float t54 = Vb[(54 * 3 + kh) * 256 + t];
            const float t55 = Vb[(55 * 3 + kh) * 256 + t];
            sS[(kh * 3 + 0) * 256 + t] = Ae[kh] - t54;   // kw0: even w <= 52
            sS[(kh * 3 + 1) * 256 + t] = Bo[kh] - t55;   // kw1: odd  w <= 53
            sS[(kh * 3 + 2) * 256 + t] = Ae[kh] - t0;    // kw2: even w >= 2
        }
        __syncthreads();

        {   // contraction: part = t>>6 handles 64 input channels, co = t&63
            const int co = t & 63, part = t >> 6;
            float a = 0.f;
#pragma unroll
            for (int k = 0; k < 9; ++k) {
                const int cb = part * 64;
#pragma unroll 8
                for (int ci = 0; ci < 64; ++ci)
                    a += sS[k * 256 + cb + ci]
                       * convw[(size_t)(k * 256 + cb + ci) * 64 + co];
            }
            pP[part][co] = a;
        }
        __syncthreads();

        if (t < 64)
            pld[t] = (pP[0][t] + pP[1][t] + pP[2][t] + pP[3][t])
                     * (1.f / 729.f) + convb[t];
        __syncthreads();

        if (t < 4) {
            float a = fcb[t];
#pragma unroll
            for (int co = 0; co < 64; ++co) a += pld[co] * fcw[co * 4 + t];
            lgt[t] = a;
            out_logits[b * 4 + t] = a;
        }
        __syncthreads();

        if (t == 0) {
            int bi = 0; float best = lgt[0];
#pragma unroll
            for (int r = 1; r < 4; ++r)
                if (lgt[r] > best) { best = lgt[r]; bi = r; }
            routes[b] = bi;
        }
    }
}

// ---------------------------------------------------------------------------
// kC: routed channel-group gather. One float4 per thread (proven config).
// total float4 = 64*56*56*16 = 3,211,264 = 12544 blocks * 256 threads.
// ---------------------------------------------------------------------------
__global__ __launch_bounds__(256) void kC_gather(
        const float* __restrict__ in, const int* __restrict__ routes,
        float* __restrict__ out) {
    const size_t idx = (size_t)blockIdx.x * 256 + threadIdx.x;  // float4 index
    const size_t pix = idx >> 4;
    const int   f4i  = (int)(idx & 15);
    const int   b    = (int)(pix / (Hn * Wn));
    const int   r    = routes[b];
    const float4 v = *(const float4*)(in + pix * (size_t)Cn
                                      + (size_t)r * RWn + (size_t)f4i * 4);
    ((float4*)out)[idx] = v;
}

extern "C" void kernel_launch(void* const* d_in, const int* in_sizes, int n_in,
                              void* d_out, int out_size, void* d_ws, size_t ws_size,
                              hipStream_t stream) {
    const float* in    = (const float*)d_in[0];
    const float* convw = (const float*)d_in[1];
    const float* convb = (const float*)d_in[2];
    const float* fcw   = (const float*)d_in[3];
    const float* fcb   = (const float*)d_in[4];
    float* out = (float*)d_out;

    const size_t vBytes = (size_t)Bn * Wn * 3 * 256 * sizeof(float);  // 11 MB
    float* V      = (float*)d_ws;
    int*   routes = (int*)((char*)d_ws + vBytes);
    int*   cnt    = routes + Bn;

    hipMemsetAsync(cnt, 0, Bn * sizeof(int), stream);   // capture-safe node
    kAB<<<Bn * BPB, 256, 0, stream>>>(in, convw, convb, fcw, fcb,
                                      V, cnt, out + XSZ, routes);
    kC_gather<<<12544, 256, 0, stream>>>(in, routes, out);
}

// Round 3
// 334.289 us; speedup vs baseline: 1.6149x; 1.6149x over previous
//
#include <hip/hip_runtime.h>
#include <cstdint>
#include <cstddef>

#define Bn 64
#define Hn 56
#define Wn 56
#define Cn 256
#define RWn 64                              // route width = 256/4
#define XSZ ((size_t)Bn * Hn * Wn * RWn)    // 12,845,056 floats
#define RSTRIDE (Wn * Cn)                   // floats between rows

__device__ __forceinline__ void f4add(float4& a, const float4& v) {
    a.x += v.x; a.y += v.y; a.z += v.z; a.w += v.w;
}
__device__ __forceinline__ float4 f4sub(const float4& a, const float4& b) {
    return make_float4(a.x - b.x, a.y - b.y, a.z - b.z, a.w - b.w);
}

// ---------------------------------------------------------------------------
// kA_col: per-(batch, column) row-class sums. One WAVE per column; pure
// accumulate loop with first/last pairs PEELED so r0/r54/r55 stay in
// registers instead of being re-fetched from (evicted) cache — saves ~11 MB
// HBM. Accumulation order unchanged (h=0,2,..,54 / 1,3,..,55) -> verified
// bit-identical in R2.
//   T0 (even h<=52) = A - r54;  T2 (even h>=2) = A - r0;  T1 (odd h<=53) = B - r55
// Grid: 64 * 14 blocks, 4 waves/block = one column per wave.
// NOTE: no cross-block handoff here — R2 showed agent-scope fences
// (L2 wbl2/inv on every block) cost 10x more than the launch they save.
// ---------------------------------------------------------------------------
__global__ __launch_bounds__(256, 4) void kA_col(
        const float* __restrict__ in, float* __restrict__ V) {
    const int blk  = blockIdx.x;
    const int b    = blk / (Wn / 4);
    const int wg   = blk - b * (Wn / 4);
    const int lane = threadIdx.x & 63;
    const int wave = threadIdx.x >> 6;
    const int w    = wg * 4 + wave;

    const float* col = in + ((size_t)b * Hn * Wn + (size_t)w) * Cn + (size_t)lane * 4;

    // peeled first pair (h = 0,1)
    const float4 r0 = *(const float4*)(col);
    const float4 r1 = *(const float4*)(col + (size_t)RSTRIDE);
    float4 A  = r0;   // even rows 0..54
    float4 Bv = r1;   // odd  rows 1..55
#pragma unroll
    for (int h = 2; h < 54; h += 2) {
        f4add(A,  *(const float4*)(col + (size_t)h * RSTRIDE));
        f4add(Bv, *(const float4*)(col + (size_t)(h + 1) * RSTRIDE));
    }
    // peeled last pair (h = 54,55)
    const float4 r54 = *(const float4*)(col + (size_t)54 * RSTRIDE);
    const float4 r55 = *(const float4*)(col + (size_t)55 * RSTRIDE);
    f4add(A,  r54);
    f4add(Bv, r55);

    const float4 T0 = f4sub(A,  r54);
    const float4 T2 = f4sub(A,  r0);
    const float4 T1 = f4sub(Bv, r55);

    float4* op = (float4*)(V + (((size_t)b * Wn + w) * 3) * 256) + lane;
    op[0]   = T0;      // cls 0, 1KB coalesced per wave
    op[64]  = T1;      // cls 1
    op[128] = T2;      // cls 2
}

// ---------------------------------------------------------------------------
// kB: one block per batch, now 512 threads (8 waves) — this kernel runs with
// only 64 blocks (25% of CUs) and is L2/L3-latency-bound on convw, so more
// waves per block = more loads in flight.
//  fold:   t<256  computes Ae[3] (even-w sums, ci=t)   -> rows kw0, kw2
//          t>=256 computes Bo[3] (odd-w sums, ci=t-256) -> row  kw1
//          (same per-class add order as before -> bit-identical sS)
//  contraction: co = t&63, part = t>>6 (8 parts x 32 ci each)
// ---------------------------------------------------------------------------
__global__ __launch_bounds__(512) void kB_logits(
        const float* __restrict__ V,
        const float* __restrict__ convw, const float* __restrict__ convb,
        const float* __restrict__ fcw,   const float* __restrict__ fcb,
        float* __restrict__ out_logits, int* __restrict__ routes) {
    const int b = blockIdx.x;
    const int t = threadIdx.x;
    __shared__ float sS[9 * 256];
    __shared__ float pP[8][64];
    __shared__ float pld[64];
    __shared__ float lgt[4];

    const float* Vb = V + (size_t)b * Wn * 3 * 256;

    if (t < 256) {                       // even-w classes: kw0, kw2
        const int ci = t;
        float Ae[3] = {0.f, 0.f, 0.f};
#pragma unroll
        for (int w = 0; w < Wn; w += 2)
#pragma unroll
            for (int kh = 0; kh < 3; ++kh)
                Ae[kh] += Vb[(w * 3 + kh) * 256 + ci];
#pragma unroll
        for (int kh = 0; kh < 3; ++kh) {
            const float t0  = Vb[(0  * 3 + kh) * 256 + ci];
            const float t54 = Vb[(54 * 3 + kh) * 256 + ci];
            sS[(kh * 3 + 0) * 256 + ci] = Ae[kh] - t54;  // kw0: even w <= 52
            sS[(kh * 3 + 2) * 256 + ci] = Ae[kh] - t0;   // kw2: even w >= 2
        }
    } else {                             // odd-w class: kw1
        const int ci = t - 256;
        float Bo[3] = {0.f, 0.f, 0.f};
#pragma unroll
        for (int w = 1; w < Wn; w += 2)
#pragma unroll
            for (int kh = 0; kh < 3; ++kh)
                Bo[kh] += Vb[(w * 3 + kh) * 256 + ci];
#pragma unroll
        for (int kh = 0; kh < 3; ++kh) {
            const float t55 = Vb[(55 * 3 + kh) * 256 + ci];
            sS[(kh * 3 + 1) * 256 + ci] = Bo[kh] - t55;  // kw1: odd w <= 53
        }
    }
    __syncthreads();

    {   // contraction: part = t>>6 handles 32 input channels, co = t&63
        const int co = t & 63, part = t >> 6;
        const int cb = part * 32;
        float a = 0.f;
#pragma unroll
        for (int k = 0; k < 9; ++k) {
#pragma unroll 8
            for (int ci = 0; ci < 32; ++ci)
                a += sS[k * 256 + cb + ci]
                   * convw[(size_t)(k * 256 + cb + ci) * 64 + co];
        }
        pP[part][co] = a;
    }
    __syncthreads();

    if (t < 64) {
        float s = pP[0][t];
#pragma unroll
        for (int p = 1; p < 8; ++p) s += pP[p][t];
        pld[t] = s * (1.f / 729.f) + convb[t];
    }
    __syncthreads();

    if (t < 4) {
        float a = fcb[t];
#pragma unroll
        for (int co = 0; co < 64; ++co) a += pld[co] * fcw[co * 4 + t];
        lgt[t] = a;
        out_logits[b * 4 + t] = a;
    }
    __syncthreads();

    if (t == 0) {
        int bi = 0; float best = lgt[0];
#pragma unroll
        for (int r = 1; r < 4; ++r) if (lgt[r] > best) { best = lgt[r]; bi = r; }
        routes[b] = bi;
    }
}

// ---------------------------------------------------------------------------
// kC: routed channel-group gather. One float4 per thread (proven config).
// total float4 = 64*56*56*16 = 3,211,264 = 12544 blocks * 256 threads.
// ---------------------------------------------------------------------------
__global__ __launch_bounds__(256) void kC_gather(
        const float* __restrict__ in, const int* __restrict__ routes,
        float* __restrict__ out) {
    const size_t idx = (size_t)blockIdx.x * 256 + threadIdx.x;  // float4 index
    const size_t pix = idx >> 4;
    const int   f4i  = (int)(idx & 15);
    const int   b    = (int)(pix / (Hn * Wn));
    const int   r    = routes[b];
    const float4 v = *(const float4*)(in + pix * (size_t)Cn
                                      + (size_t)r * RWn + (size_t)f4i * 4);
    ((float4*)out)[idx] = v;
}

extern "C" void kernel_launch(void* const* d_in, const int* in_sizes, int n_in,
                              void* d_out, int out_size, void* d_ws, size_t ws_size,
                              hipStream_t stream) {
    const float* in    = (const float*)d_in[0];
    const float* convw = (const float*)d_in[1];
    const float* convb = (const float*)d_in[2];
    const float* fcw   = (const float*)d_in[3];
    const float* fcb   = (const float*)d_in[4];
    float* out = (float*)d_out;

    const size_t vBytes = (size_t)Bn * Wn * 3 * 256 * sizeof(float);  // 11 MB
    float* V      = (float*)d_ws;
    int*   routes = (int*)((char*)d_ws + vBytes);

    kA_col   <<<Bn * (Wn / 4), 256, 0, stream>>>(in, V);
    kB_logits<<<Bn,            512, 0, stream>>>(V, convw, convb, fcw, fcb,
                                                 out + XSZ, routes);
    kC_gather<<<12544,         256, 0, stream>>>(in, routes, out);
}

// Round 4
// 332.276 us; speedup vs baseline: 1.6247x; 1.0061x over previous
//
#include <hip/hip_runtime.h>
#include <cstdint>
#include <cstddef>

#define Bn 64
#define Hn 56
#define Wn 56
#define Cn 256
#define RWn 64                              // route width = 256/4
#define XSZ ((size_t)Bn * Hn * Wn * RWn)    // 12,845,056 floats
#define RSTRIDE (Wn * Cn)                   // floats between rows

__device__ __forceinline__ void f4add(float4& a, const float4& v) {
    a.x += v.x; a.y += v.y; a.z += v.z; a.w += v.w;
}
__device__ __forceinline__ float4 f4sub(const float4& a, const float4& b) {
    return make_float4(a.x - b.x, a.y - b.y, a.z - b.z, a.w - b.w);
}

// ---------------------------------------------------------------------------
// kA_col: per-(batch, column) row-class sums, one WAVE per column, with the
// proven peeled pure-accumulate H-loop (r0/r54/r55 stay in registers).
// NEW vs R3: the 4 columns of a block are PRE-FOLDED in LDS before leaving
// the block. Instead of writing full T[3][256] per column (11 MB), we write:
//   P[b][wg][s][kh][ci]  s=0: T[w=4wg]+T[4wg+2] (even cols), s=1: odd cols
//   E[b][e][kh][ci]      raw T of edge columns e={w0, w54, w55}
// -> 5.8 MB instead of 11 MB, and kB's fold shrinks 56 terms -> 14.
// Global load pattern / occupancy identical to the proven R3 kernel.
// NOTE: no cross-block handoff — R2 showed agent-scope fences cost 10x the
// launch they save on gfx950 (per-XCD L2 wbl2/inv storm).
// ---------------------------------------------------------------------------
__global__ __launch_bounds__(256, 4) void kA_col(
        const float* __restrict__ in, float* __restrict__ P,
        float* __restrict__ E) {
    const int blk  = blockIdx.x;
    const int b    = blk / (Wn / 4);
    const int wg   = blk - b * (Wn / 4);
    const int lane = threadIdx.x & 63;
    const int wave = threadIdx.x >> 6;
    const int w    = wg * 4 + wave;

    __shared__ float4 Wl[4][3][64];      // [wave][kh][ci/4]

    const float* col = in + ((size_t)b * Hn * Wn + (size_t)w) * Cn
                          + (size_t)lane * 4;

    // peeled first pair (h = 0,1)
    const float4 r0 = *(const float4*)(col);
    const float4 r1 = *(const float4*)(col + (size_t)RSTRIDE);
    float4 A  = r0;   // even rows 0..54
    float4 Bv = r1;   // odd  rows 1..55
#pragma unroll
    for (int h = 2; h < 54; h += 2) {
        f4add(A,  *(const float4*)(col + (size_t)h * RSTRIDE));
        f4add(Bv, *(const float4*)(col + (size_t)(h + 1) * RSTRIDE));
    }
    // peeled last pair (h = 54,55)
    const float4 r54 = *(const float4*)(col + (size_t)54 * RSTRIDE);
    const float4 r55 = *(const float4*)(col + (size_t)55 * RSTRIDE);
    f4add(A,  r54);
    f4add(Bv, r55);

    const float4 T0 = f4sub(A,  r54);    // even h <= 52 (kh = 0)
    const float4 T1 = f4sub(Bv, r55);    // odd  h <= 53 (kh = 1)
    const float4 T2 = f4sub(A,  r0);     // even h >= 2  (kh = 2)

    Wl[wave][0][lane] = T0;
    Wl[wave][1][lane] = T1;
    Wl[wave][2][lane] = T2;

    // raw edge columns -> E[b][e][kh][ci]   (wave-uniform condition)
    if (w == 0 || w == 54 || w == 55) {
        const int e = (w == 0) ? 0 : (w == 54 ? 1 : 2);
        float4* ep = (float4*)(E + (size_t)(b * 3 + e) * 3 * 256) + lane;
        ep[0]   = T0;
        ep[64]  = T1;
        ep[128] = T2;
    }
    __syncthreads();

    // fold the block's 4 columns: even = wave0+wave2, odd = wave1+wave3
    const float* Wf = (const float*)Wl;              // [wave*3+kh][ci]
    const int t = threadIdx.x;                       // ci = t
    float* Pb = P + (size_t)(b * (Wn / 4) + wg) * 2 * 768;
#pragma unroll
    for (int kh = 0; kh < 3; ++kh) {
        const float ev = Wf[(0 * 3 + kh) * 256 + t] + Wf[(2 * 3 + kh) * 256 + t];
        const float od = Wf[(1 * 3 + kh) * 256 + t] + Wf[(3 * 3 + kh) * 256 + t];
        Pb[       kh * 256 + t] = ev;    // s=0: even columns
        Pb[768 +  kh * 256 + t] = od;    // s=1: odd columns
    }
}

// ---------------------------------------------------------------------------
// kB: one block per batch, 512 threads (R3-proven split: t<256 even classes,
// t>=256 odd class). Fold is now 14 pre-folded partials + 1-2 edge loads per
// (kh,ci) instead of 28 columns — half the strided loads on a 64-block
// (latency-bound) kernel. Contraction/logits/argmax verbatim from R3.
// ---------------------------------------------------------------------------
__global__ __launch_bounds__(512) void kB_logits(
        const float* __restrict__ P,     const float* __restrict__ E,
        const float* __restrict__ convw, const float* __restrict__ convb,
        const float* __restrict__ fcw,   const float* __restrict__ fcb,
        float* __restrict__ out_logits, int* __restrict__ routes) {
    const int b = blockIdx.x;
    const int t = threadIdx.x;
    __shared__ float sS[9 * 256];
    __shared__ float pP[8][64];
    __shared__ float pld[64];
    __shared__ float lgt[4];

    const float* Pb = P + (size_t)b * (Wn / 4) * 2 * 768;
    const float* Eb = E + (size_t)b * 3 * 3 * 256;

    if (t < 256) {                       // even-w classes: kw0, kw2
        const int ci = t;
#pragma unroll
        for (int kh = 0; kh < 3; ++kh) {
            float ev = 0.f;
#pragma unroll
            for (int wg = 0; wg < 14; ++wg)
                ev += Pb[(wg * 2 + 0) * 768 + kh * 256 + ci];
            const float t0  = Eb[(0 * 3 + kh) * 256 + ci];
            const float t54 = Eb[(1 * 3 + kh) * 256 + ci];
            sS[(kh * 3 + 0) * 256 + ci] = ev - t54;   // kw0: even w <= 52
            sS[(kh * 3 + 2) * 256 + ci] = ev - t0;    // kw2: even w >= 2
        }
    } else {                             // odd-w class: kw1
        const int ci = t - 256;
#pragma unroll
        for (int kh = 0; kh < 3; ++kh) {
            float od = 0.f;
#pragma unroll
            for (int wg = 0; wg < 14; ++wg)
                od += Pb[(wg * 2 + 1) * 768 + kh * 256 + ci];
            const float t55 = Eb[(2 * 3 + kh) * 256 + ci];
            sS[(kh * 3 + 1) * 256 + ci] = od - t55;   // kw1: odd w <= 53
        }
    }
    __syncthreads();

    {   // contraction: part = t>>6 handles 32 input channels, co = t&63
        const int co = t & 63, part = t >> 6;
        const int cb = part * 32;
        float a = 0.f;
#pragma unroll
        for (int k = 0; k < 9; ++k) {
#pragma unroll 8
            for (int ci = 0; ci < 32; ++ci)
                a += sS[k * 256 + cb + ci]
                   * convw[(size_t)(k * 256 + cb + ci) * 64 + co];
        }
        pP[part][co] = a;
    }
    __syncthreads();

    if (t < 64) {
        float s = pP[0][t];
#pragma unroll
        for (int p = 1; p < 8; ++p) s += pP[p][t];
        pld[t] = s * (1.f / 729.f) + convb[t];
    }
    __syncthreads();

    if (t < 4) {
        float a = fcb[t];
#pragma unroll
        for (int co = 0; co < 64; ++co) a += pld[co] * fcw[co * 4 + t];
        lgt[t] = a;
        out_logits[b * 4 + t] = a;
    }
    __syncthreads();

    if (t == 0) {
        int bi = 0; float best = lgt[0];
#pragma unroll
        for (int r = 1; r < 4; ++r) if (lgt[r] > best) { best = lgt[r]; bi = r; }
        routes[b] = bi;
    }
}

// ---------------------------------------------------------------------------
// kC: routed channel-group gather. One float4 per thread (proven config).
// total float4 = 64*56*56*16 = 3,211,264 = 12544 blocks * 256 threads.
// ---------------------------------------------------------------------------
__global__ __launch_bounds__(256) void kC_gather(
        const float* __restrict__ in, const int* __restrict__ routes,
        float* __restrict__ out) {
    const size_t idx = (size_t)blockIdx.x * 256 + threadIdx.x;  // float4 index
    const size_t pix = idx >> 4;
    const int   f4i  = (int)(idx & 15);
    const int   b    = (int)(pix / (Hn * Wn));
    const int   r    = routes[b];
    const float4 v = *(const float4*)(in + pix * (size_t)Cn
                                      + (size_t)r * RWn + (size_t)f4i * 4);
    ((float4*)out)[idx] = v;
}

extern "C" void kernel_launch(void* const* d_in, const int* in_sizes, int n_in,
                              void* d_out, int out_size, void* d_ws, size_t ws_size,
                              hipStream_t stream) {
    const float* in    = (const float*)d_in[0];
    const float* convw = (const float*)d_in[1];
    const float* convb = (const float*)d_in[2];
    const float* fcw   = (const float*)d_in[3];
    const float* fcb   = (const float*)d_in[4];
    float* out = (float*)d_out;

    const size_t pFloats = (size_t)Bn * (Wn / 4) * 2 * 768;   // 1,376,256
    const size_t eFloats = (size_t)Bn * 3 * 3 * 256;          //   147,456
    float* P      = (float*)d_ws;
    float* E      = P + pFloats;
    int*   routes = (int*)(E + eFloats);

    kA_col   <<<Bn * (Wn / 4), 256, 0, stream>>>(in, P, E);
    kB_logits<<<Bn,            512, 0, stream>>>(P, E, convw, convb, fcw, fcb,
                                                 out + XSZ, routes);
    kC_gather<<<12544,         256, 0, stream>>>(in, routes, out);
}